// Round 9
// baseline (190.479 us; speedup 1.0000x reference)
//
#include <hip/hip_runtime.h>
#include <math.h>

// GCN 2-layer, N=100K, E=3.2M, feat 1->16->2, log_softmax.
//
// R5: sort tile in LDS, stream out coalesced. R6: coop monolith = TLP death.
// R7: random global atomicAdd = ~32B HBM RMW per 4B atomic. Never.
// R8: EPB 4096 + int4 loads fixed scatter. R9: grid-imbalance fix neutral.
// R10: reorder pass +4us only. R11: radix pipeline neutral (187.6).
//   => Three different data layouts all ~185us: agg/scatter are neither
//      traffic- nor chain-bound. Audit: R11 scatter2 LDS = 56.4KB at 512thr
//      -> 2 blocks/CU = 16 waves/CU (worst in pipeline, all blocks resident
//      -> pass time ~ max-block latency, doubled by the occupancy loss).
// R12 (this round): (1) scatter2 at 1024 threads -> 2 blocks/CU x 16 waves
//      = 32 waves/CU (full); flat 1024-thread shfl scan. (2) agg bodies use
//      ulonglong2 x4 (8 edges/thread/iter, 16B/lane) with head/tail fixup.

static constexpr int BLOCK_S   = 512;    // hist threads
static constexpr int BLOCK_S2  = 1024;   // scatter2 threads (32 waves/CU)
static constexpr int EPB       = 4096;   // edges per tile
static constexpr int VITERS    = EPB / (BLOCK_S * 4);   // 2 (hist int4 groups)
static constexpr int CHUNK     = 128;    // nodes per bucket (pow2)
static constexpr int LOG_CHUNK = 7;
static constexpr int BLOCK_A   = 512;    // agg threads
static constexpr int MAXNB     = 1024;   // max buckets (N <= 131072)
static constexpr int MAXBLK    = 1024;   // max tiles (E <= 4.19M)

// ============ 512-thread pair-wise inclusive scan (2 barriers) ============
__device__ __forceinline__ unsigned int incl_scan512(unsigned int v,
                                                     unsigned int* wsum, int t) {
    unsigned int x = v;
#pragma unroll
    for (int off = 1; off < 64; off <<= 1) {
        unsigned int y = __shfl_up(x, off, 64);
        if ((t & 63) >= off) x += y;
    }
    if ((t & 63) == 63) wsum[t >> 6] = x;
    __syncthreads();
    if (t < 8) {
        unsigned int s = wsum[t];
#pragma unroll
        for (int off = 1; off < 8; off <<= 1) {
            unsigned int y = __shfl_up(s, off, 64);
            if (t >= off) s += y;
        }
        wsum[t] = s;
    }
    __syncthreads();
    return x + ((t >= 64) ? wsum[(t >> 6) - 1] : 0u);
}

// ============ 1024-thread flat inclusive scan (2 barriers) ============
__device__ __forceinline__ unsigned int incl_scan1024(unsigned int v,
                                                      unsigned int* wsum, int t) {
    unsigned int x = v;
#pragma unroll
    for (int off = 1; off < 64; off <<= 1) {
        unsigned int y = __shfl_up(x, off, 64);
        if ((t & 63) >= off) x += y;
    }
    if ((t & 63) == 63) wsum[t >> 6] = x;   // 16 wave sums
    __syncthreads();
    if (t < 16) {
        unsigned int s = wsum[t];
#pragma unroll
        for (int off = 1; off < 16; off <<= 1) {
            unsigned int y = __shfl_up(s, off, 64);
            if (t >= off) s += y;
        }
        wsum[t] = s;
    }
    __syncthreads();
    return x + ((t >= 64) ? wsum[(t >> 6) - 1] : 0u);
}

// ======================= K1: per-tile histogram =======================
__global__ __launch_bounds__(BLOCK_S) void hist_kernel(
    const int* __restrict__ dst,
    unsigned int* __restrict__ histT,          // [nb][nblk]
    int E, int nb, int nblk) {
    __shared__ unsigned int hist[MAXNB];       // 4 KB
    const int blk  = blockIdx.x;
    const int base = blk * EPB;
    const int nE   = min(EPB, E - base);
    const int t    = threadIdx.x;

    hist[t]           = 0u;
    hist[t + BLOCK_S] = 0u;
    __syncthreads();

#pragma unroll
    for (int i = 0; i < VITERS; ++i) {
        const int k = 4 * t + i * 4 * BLOCK_S;
        if (k < nE) {
            const int4 d4 = *reinterpret_cast<const int4*>(&dst[base + k]);
            atomicAdd(&hist[(unsigned int)d4.x >> LOG_CHUNK], 1u);
            atomicAdd(&hist[(unsigned int)d4.y >> LOG_CHUNK], 1u);
            atomicAdd(&hist[(unsigned int)d4.z >> LOG_CHUNK], 1u);
            atomicAdd(&hist[(unsigned int)d4.w >> LOG_CHUNK], 1u);
        }
    }
    __syncthreads();
    if (2 * t < nb)     histT[(size_t)(2 * t) * nblk + blk]     = hist[2 * t];
    if (2 * t + 1 < nb) histT[(size_t)(2 * t + 1) * nblk + blk] = hist[2 * t + 1];
}

// ======================= K2a: per-bucket prefix over tiles =======================
__global__ __launch_bounds__(BLOCK_S) void rowscan_kernel(
    const unsigned int* __restrict__ histT,    // [nb][nblk]
    unsigned int* __restrict__ prefT,          // [nb][nblk] exclusive
    unsigned int* __restrict__ bucketTotal,    // [nb]
    int nblk) {
    __shared__ unsigned int wsum[8];
    const int b = blockIdx.x, t = threadIdx.x;
    const int e0 = 2 * t;
    unsigned int v0 = 0, v1 = 0;
    if (e0 < nblk) {                            // nblk even -> pair in-bounds
        const uint2 r = *reinterpret_cast<const uint2*>(&histT[(size_t)b * nblk + e0]);
        v0 = r.x; v1 = r.y;
    }
    const unsigned int incl = incl_scan512(v0 + v1, wsum, t);
    const unsigned int ex0  = incl - v0 - v1;
    const unsigned int ex1  = ex0 + v0;
    if (e0 < nblk)
        *reinterpret_cast<uint2*>(&prefT[(size_t)b * nblk + e0]) = make_uint2(ex0, ex1);
    if (t == BLOCK_S - 1) bucketTotal[b] = incl;
}

// ======================= K2b: scan over buckets =======================
__global__ __launch_bounds__(BLOCK_S) void bscan_kernel(
    const unsigned int* __restrict__ bucketTotal,
    unsigned int* __restrict__ bucketStart,    // [nb+1]
    int nb) {
    __shared__ unsigned int wsum[8];
    const int t = threadIdx.x;
    const unsigned int v0 = (2 * t < nb)     ? bucketTotal[2 * t]     : 0u;
    const unsigned int v1 = (2 * t + 1 < nb) ? bucketTotal[2 * t + 1] : 0u;
    const unsigned int incl = incl_scan512(v0 + v1, wsum, t);
    const unsigned int ex0  = incl - v0 - v1;
    const unsigned int ex1  = ex0 + v0;
    if (2 * t < nb)     bucketStart[2 * t]     = ex0;
    if (2 * t + 1 < nb) bucketStart[2 * t + 1] = ex1;
    if (t == BLOCK_S - 1) bucketStart[nb] = incl;   // == E
}

// ============ K3: direct scatter to bucket-major payload2 (1024 thr) ============
__global__ __launch_bounds__(BLOCK_S2) void scatter2_kernel(
    const int* __restrict__ src, const int* __restrict__ dst,
    const float* __restrict__ w,
    const unsigned int* __restrict__ prefT,
    const unsigned int* __restrict__ bucketStart,
    unsigned long long* __restrict__ payload2,  // [E]
    int E, int nb, int nblk) {
    __shared__ unsigned long long pbuf[EPB];    // 32 KB
    __shared__ unsigned int gaddrA[EPB];        // 16 KB final addr per slot
    __shared__ unsigned int hist[MAXNB];        // 4 KB (counts -> cursor)
    __shared__ int          adjp[MAXNB];        // 4 KB globalBase - localExcl
    __shared__ unsigned int wsum[16];
    const int blk  = blockIdx.x;
    const int base = blk * EPB;
    const int nE   = min(EPB, E - base);
    const int t    = threadIdx.x;

    hist[t] = 0u;                               // 1024 threads cover MAXNB
    __syncthreads();

    int4 d4 = make_int4(0, 0, 0, 0);            // single int4 group (VITERS2=1)
    const int k0 = 4 * t;
    if (k0 < nE) {
        d4 = *reinterpret_cast<const int4*>(&dst[base + k0]);
        atomicAdd(&hist[(unsigned int)d4.x >> LOG_CHUNK], 1u);
        atomicAdd(&hist[(unsigned int)d4.y >> LOG_CHUNK], 1u);
        atomicAdd(&hist[(unsigned int)d4.z >> LOG_CHUNK], 1u);
        atomicAdd(&hist[(unsigned int)d4.w >> LOG_CHUNK], 1u);
    }
    __syncthreads();

    // flat scan: thread t owns bucket t
    const unsigned int val  = hist[t];
    const unsigned int incl = incl_scan1024(val, wsum, t);
    const unsigned int excl = incl - val;
    if (t < nb)
        adjp[t] = (int)(bucketStart[t] + prefT[(size_t)t * nblk + blk]) - (int)excl;
    hist[t] = excl;                             // -> cursor
    __syncthreads();

    if (k0 < nE) {
        const int4   s4 = *reinterpret_cast<const int4*>(&src[base + k0]);
        const float4 w4 = *reinterpret_cast<const float4*>(&w[base + k0]);
#define SCAT_ONE(dd, ss, ww)                                                  \
        {                                                                     \
            const int bkt = (int)((unsigned int)(dd) >> LOG_CHUNK);           \
            const unsigned int slot = atomicAdd(&hist[bkt], 1u);              \
            pbuf[slot] =                                                      \
                ((unsigned long long)__float_as_uint(ww) << 32) |             \
                ((unsigned int)(ss) << LOG_CHUNK) |                           \
                (unsigned int)((dd) & (CHUNK - 1));                           \
            gaddrA[slot] = (unsigned int)(adjp[bkt] + (int)slot);             \
        }
        SCAT_ONE(d4.x, s4.x, w4.x)
        SCAT_ONE(d4.y, s4.y, w4.y)
        SCAT_ONE(d4.z, s4.z, w4.z)
        SCAT_ONE(d4.w, s4.w, w4.w)
#undef SCAT_ONE
    }
    __syncthreads();
    // write-out: ascending global addresses (runs contiguous, gaps between)
    for (int k = t; k < nE; k += BLOCK_S2)
        payload2[gaddrA[k]] = pbuf[k];
}

// ============ agg bodies: ulonglong2 x4 = 8 edges/thread/iter ============
// PROC1(p): one edge. Head/tail fixup keeps 16B alignment for pair loads.

#define AGGV(PROC1)                                                           \
    unsigned int beg = bucketStart[b], end = bucketStart[b + 1];              \
    if (beg < end && (beg & 1u)) {                                            \
        if (t == 0) { const unsigned long long p = payload2[beg]; PROC1(p) }  \
        ++beg;                                                                \
    }                                                                         \
    const unsigned int rem   = end - beg;                                     \
    const unsigned int npair = rem >> 1;                                      \
    unsigned int j = t;                                                       \
    for (; j + 3u * BLOCK_A < npair; j += 4u * BLOCK_A) {                     \
        const ulonglong2 q0 = *reinterpret_cast<const ulonglong2*>(&payload2[beg + 2u * j]); \
        const ulonglong2 q1 = *reinterpret_cast<const ulonglong2*>(&payload2[beg + 2u * (j + BLOCK_A)]); \
        const ulonglong2 q2 = *reinterpret_cast<const ulonglong2*>(&payload2[beg + 2u * (j + 2u * BLOCK_A)]); \
        const ulonglong2 q3 = *reinterpret_cast<const ulonglong2*>(&payload2[beg + 2u * (j + 3u * BLOCK_A)]); \
        { const unsigned long long p = q0.x; PROC1(p) }                       \
        { const unsigned long long p = q0.y; PROC1(p) }                       \
        { const unsigned long long p = q1.x; PROC1(p) }                       \
        { const unsigned long long p = q1.y; PROC1(p) }                       \
        { const unsigned long long p = q2.x; PROC1(p) }                       \
        { const unsigned long long p = q2.y; PROC1(p) }                       \
        { const unsigned long long p = q3.x; PROC1(p) }                       \
        { const unsigned long long p = q3.y; PROC1(p) }                       \
    }                                                                         \
    for (; j < npair; j += BLOCK_A) {                                         \
        const ulonglong2 q = *reinterpret_cast<const ulonglong2*>(&payload2[beg + 2u * j]); \
        { const unsigned long long p = q.x; PROC1(p) }                        \
        { const unsigned long long p = q.y; PROC1(p) }                        \
    }                                                                         \
    if ((rem & 1u) && t == 0) {                                               \
        const unsigned long long p = payload2[end - 1u]; PROC1(p)             \
    }

// ======================= K4: deg -> dinv, xd =======================
__global__ __launch_bounds__(BLOCK_A) void deg2_kernel(
    const unsigned long long* __restrict__ payload2,
    const unsigned int* __restrict__ bucketStart,
    const float* __restrict__ x,
    float* __restrict__ dinv, float* __restrict__ xd,
    int N, int nb) {
    __shared__ float acc[CHUNK];
    const int b = blockIdx.x, t = threadIdx.x;
    if (t < CHUNK) acc[t] = 0.0f;
    __syncthreads();
#define PROC_DEG(p)                                                           \
    atomicAdd(&acc[(unsigned int)(p) & (CHUNK - 1)],                          \
              __uint_as_float((unsigned int)((p) >> 32)));
    AGGV(PROC_DEG)
#undef PROC_DEG
    __syncthreads();
    const int n = b * CHUNK + t;
    if (t < CHUNK && n < N) {
        const float d = acc[t] + 1.0f;           // self-loop fill 1.0
        const float r = (d > 0.0f) ? rsqrtf(d) : 0.0f;
        dinv[n] = r;
        xd[n]   = r * x[n];
    }
}

// ======================= K5: s -> relu-MLP -> gd =======================
__global__ __launch_bounds__(BLOCK_A) void s_gamma2_kernel(
    const unsigned long long* __restrict__ payload2,
    const unsigned int* __restrict__ bucketStart,
    const float* __restrict__ dinv,
    const float* __restrict__ xd,
    const float* __restrict__ W1,    // [16]
    const float* __restrict__ b1,    // [16]
    const float* __restrict__ W2,    // [16][2]
    float* __restrict__ gd, int N, int nb) {
    __shared__ float acc[CHUNK];
    const int b = blockIdx.x, t = threadIdx.x;
    if (t < CHUNK) acc[t] = 0.0f;
    __syncthreads();
#define PROC_S(p)                                                             \
    atomicAdd(&acc[(unsigned int)(p) & (CHUNK - 1)],                          \
              __uint_as_float((unsigned int)((p) >> 32)) *                    \
                  xd[(int)(((unsigned int)(p)) >> LOG_CHUNK)]);
    AGGV(PROC_S)
#undef PROC_S
    __syncthreads();
    const int n = b * CHUNK + t;
    if (t < CHUNK && n < N) {
        const float dv = dinv[n];
        const float sv = dv * (acc[t] + xd[n]);   // + self-loop dv*dv*x[n]
        float g = 0.0f;
#pragma unroll
        for (int f = 0; f < 16; ++f) {
            const float h = fmaxf(sv * W1[f] + b1[f], 0.0f);   // relu(layer1)
            g += h * (W2[2 * f + 1] - W2[2 * f + 0]);          // gamma = g1-g0
        }
        gd[n] = dv * g;                           // pre-scaled for layer 2
    }
}

// ======================= K6: d -> log_softmax out =======================
__global__ __launch_bounds__(BLOCK_A) void d_out2_kernel(
    const unsigned long long* __restrict__ payload2,
    const unsigned int* __restrict__ bucketStart,
    const float* __restrict__ dinv,
    const float* __restrict__ gd,
    const float* __restrict__ b2,    // [2]
    float* __restrict__ out, int N, int nb) {
    __shared__ float acc[CHUNK];
    const int b = blockIdx.x, t = threadIdx.x;
    if (t < CHUNK) acc[t] = 0.0f;
    __syncthreads();
#define PROC_D(p)                                                             \
    atomicAdd(&acc[(unsigned int)(p) & (CHUNK - 1)],                          \
              __uint_as_float((unsigned int)((p) >> 32)) *                    \
                  gd[(int)(((unsigned int)(p)) >> LOG_CHUNK)]);
    AGGV(PROC_D)
#undef PROC_D
    __syncthreads();
    const int n = b * CHUNK + t;
    if (t < CHUNK && n < N) {
        const float dv = dinv[n];
        const float d = dv * (acc[t] + gd[n]) + (b2[1] - b2[0]);
        // 2-class log_softmax from d = a1 - a0 (stable)
        const float lse = fmaxf(d, 0.0f) + log1pf(expf(-fabsf(d)));
        out[2 * n + 0] = -lse;
        out[2 * n + 1] = d - lse;
    }
}

// ======================= fallback: R3 global-atomic path =======================

static constexpr int BLOCK = 256;

__global__ void zero_kernel(float* __restrict__ a, float* __restrict__ b, int n2) {
    int i = blockIdx.x * blockDim.x + threadIdx.x;
    if (i < n2) { a[i] = 0.0f; b[i] = 0.0f; }
}
__global__ void deg_kernel(const int* __restrict__ dst, const float* __restrict__ w,
                           float* __restrict__ deg, int E) {
    int e = blockIdx.x * blockDim.x + threadIdx.x;
    if (e < E) atomicAdd(&deg[dst[e]], w[e]);
}
__global__ void dinv_kernel(float* __restrict__ deg, int N) {
    int n = blockIdx.x * blockDim.x + threadIdx.x;
    if (n < N) {
        float d = deg[n] + 1.0f;
        deg[n] = (d > 0.0f) ? rsqrtf(d) : 0.0f;
    }
}
__global__ void s_kernel(const int* __restrict__ src, const int* __restrict__ dst,
                         const float* __restrict__ w, const float* __restrict__ dinv,
                         const float* __restrict__ x, float* __restrict__ s, int E) {
    int e = blockIdx.x * blockDim.x + threadIdx.x;
    if (e < E) {
        int si = src[e], di = dst[e];
        atomicAdd(&s[di], dinv[si] * w[e] * dinv[di] * x[si]);
    }
}
__global__ void g_kernel(const float* __restrict__ s, const float* __restrict__ dinv,
                         const float* __restrict__ x, const float* __restrict__ W1,
                         const float* __restrict__ b1, const float* __restrict__ W2,
                         float2* __restrict__ g, int N) {
    int n = blockIdx.x * blockDim.x + threadIdx.x;
    if (n < N) {
        float dv = dinv[n];
        float sv = s[n] + dv * dv * x[n];
        float g0 = 0.0f, g1 = 0.0f;
#pragma unroll
        for (int f = 0; f < 16; ++f) {
            float h = fmaxf(sv * W1[f] + b1[f], 0.0f);
            g0 += h * W2[2 * f + 0];
            g1 += h * W2[2 * f + 1];
        }
        g[n] = make_float2(g0, g1);
    }
}
__global__ void agg2_kernel(const int* __restrict__ src, const int* __restrict__ dst,
                            const float* __restrict__ w, const float* __restrict__ dinv,
                            const float2* __restrict__ g, float* __restrict__ agg, int E) {
    int e = blockIdx.x * blockDim.x + threadIdx.x;
    if (e < E) {
        int si = src[e], di = dst[e];
        float norm = dinv[si] * w[e] * dinv[di];
        float2 gv = g[si];
        atomicAdd(&agg[2 * di + 0], norm * gv.x);
        atomicAdd(&agg[2 * di + 1], norm * gv.y);
    }
}
__global__ void out_kernel(float* __restrict__ out, const float* __restrict__ dinv,
                           const float2* __restrict__ g, const float* __restrict__ b2, int N) {
    int n = blockIdx.x * blockDim.x + threadIdx.x;
    if (n < N) {
        float dv2 = dinv[n] * dinv[n];
        float2 gv = g[n];
        float a0 = out[2 * n + 0] + dv2 * gv.x + b2[0];
        float a1 = out[2 * n + 1] + dv2 * gv.y + b2[1];
        float m = fmaxf(a0, a1);
        float lse = m + logf(expf(a0 - m) + expf(a1 - m));
        out[2 * n + 0] = a0 - lse;
        out[2 * n + 1] = a1 - lse;
    }
}

// ======================= launch =======================

extern "C" void kernel_launch(void* const* d_in, const int* in_sizes, int n_in,
                              void* d_out, int out_size, void* d_ws, size_t ws_size,
                              hipStream_t stream) {
    const float* x  = (const float*)d_in[0];
    const int*   ei = (const int*)d_in[1];     // [2, E] delivered as int32
    const float* w  = (const float*)d_in[2];
    const float* W1 = (const float*)d_in[3];
    const float* b1 = (const float*)d_in[4];
    const float* W2 = (const float*)d_in[5];
    const float* b2 = (const float*)d_in[6];
    float* out = (float*)d_out;

    const int N = in_sizes[0];
    const int E = in_sizes[2];
    const int* src = ei;
    const int* dst = ei + E;

    const int nb   = (N + CHUNK - 1) / CHUNK;   // 782
    const int nblk = (E + EPB - 1) / EPB;       // 782

    // ws layout (16B-aligned sections):
    // payload2 | histT | prefT | bucketTotal | bucketStart | dinv | xd | gd
    size_t off = 0;
    auto align16 = [](size_t v) { return (v + 15) & ~(size_t)15; };
    size_t payload2_off = off;  off = align16(off + (size_t)E * 8);
    size_t histT_off    = off;  off = align16(off + (size_t)nb * nblk * 4);
    size_t prefT_off    = off;  off = align16(off + (size_t)nb * nblk * 4);
    size_t btot_off     = off;  off = align16(off + (size_t)nb * 4);
    size_t bstart_off   = off;  off = align16(off + (size_t)(nb + 1) * 4);
    size_t dinv_off     = off;  off = align16(off + (size_t)N * 4);
    size_t xd_off       = off;  off = align16(off + (size_t)N * 4);
    size_t gd_off       = off;  off = align16(off + (size_t)N * 4);
    const size_t required = off;

    const bool fits = (nb <= MAXNB && nblk <= MAXBLK && (nblk & 1) == 0 &&
                       (E % 4) == 0 && ws_size >= required);

    if (fits) {
        char* wsb = (char*)d_ws;
        unsigned long long* payload2 = (unsigned long long*)(wsb + payload2_off);
        unsigned int* histT       = (unsigned int*)(wsb + histT_off);
        unsigned int* prefT       = (unsigned int*)(wsb + prefT_off);
        unsigned int* bucketTotal = (unsigned int*)(wsb + btot_off);
        unsigned int* bucketStart = (unsigned int*)(wsb + bstart_off);
        float* dinv = (float*)(wsb + dinv_off);
        float* xd   = (float*)(wsb + xd_off);
        float* gd   = (float*)(wsb + gd_off);

        hist_kernel    <<<nblk, BLOCK_S,  0, stream>>>(dst, histT, E, nb, nblk);
        rowscan_kernel <<<nb,   BLOCK_S,  0, stream>>>(histT, prefT, bucketTotal, nblk);
        bscan_kernel   <<<1,    BLOCK_S,  0, stream>>>(bucketTotal, bucketStart, nb);
        scatter2_kernel<<<nblk, BLOCK_S2, 0, stream>>>(src, dst, w, prefT, bucketStart,
                                                       payload2, E, nb, nblk);
        deg2_kernel    <<<nb,   BLOCK_A,  0, stream>>>(payload2, bucketStart, x,
                                                       dinv, xd, N, nb);
        s_gamma2_kernel<<<nb,   BLOCK_A,  0, stream>>>(payload2, bucketStart, dinv, xd,
                                                       W1, b1, W2, gd, N, nb);
        d_out2_kernel  <<<nb,   BLOCK_A,  0, stream>>>(payload2, bucketStart, dinv, gd,
                                                       b2, out, N, nb);
    } else {
        // R3 fallback: global-atomic path (needs 4N floats of ws)
        float*  ws   = (float*)d_ws;
        float*  dinv = ws;
        float*  s    = ws + (size_t)N;
        float2* g    = (float2*)(ws + (size_t)2 * N);
        const int gridE  = (E + BLOCK - 1) / BLOCK;
        const int gridN  = (N + BLOCK - 1) / BLOCK;
        const int gridN2 = (2 * N + BLOCK - 1) / BLOCK;
        zero_kernel<<<gridN2, BLOCK, 0, stream>>>(ws, out, 2 * N);
        deg_kernel <<<gridE,  BLOCK, 0, stream>>>(dst, w, dinv, E);
        dinv_kernel<<<gridN,  BLOCK, 0, stream>>>(dinv, N);
        s_kernel   <<<gridE,  BLOCK, 0, stream>>>(src, dst, w, dinv, x, s, E);
        g_kernel   <<<gridN,  BLOCK, 0, stream>>>(s, dinv, x, W1, b1, W2, g, N);
        agg2_kernel<<<gridE,  BLOCK, 0, stream>>>(src, dst, w, dinv, g, out, E);
        out_kernel <<<gridN,  BLOCK, 0, stream>>>(out, dinv, g, b2, N);
    }
}

// Round 13
// 178.714 us; speedup vs baseline: 1.0658x; 1.0658x over previous
//
#include <hip/hip_runtime.h>
#include <math.h>

// GCN 2-layer, N=100K, E=3.2M, feat 1->16->2, log_softmax.
//
// Lessons ledger:
// R5: LDS-sort tile, coalesced stream-out. R6: coop monolith = TLP death.
// R7: random global atomicAdd = ~32B HBM RMW per 4B atomic. Never.
// R8: EPB 4096 + int4 loads fixed scatter. R9: grid-imbalance fix neutral.
// R10: regroup-in-pass-A dataflow, 4 dispatches: BEST measured (182.8).
// R11/R12: radix 7-dispatch pipelines: 187.6/190.5 — dispatch count costs
//   ~1.5-2us each; chain/traffic/occupancy levers all neutral.
// R13 (resubmitted 4th time; 3 timeouts + 1 container failure, never
//   measured): consolidate to minimum dispatches (4) + coarse geometry:
//   CHUNK 256 (nb=391: total prologue work halves vs 782 blocks),
//   BLOCK_A 1024 (one 4-wide ulonglong2 iter covers an 8K-edge bucket),
//   flat 1024-thread scan in pass A. PAD=TABCAP=10240 (+16 sigma; overflow
//   -> SENT -> B/C table-free binary-search fallback, correctness only).
//   PRE-COMMIT: if >=181us, plateau is structural (fill 44 + drains ~12 +
//   latency floor); write ceiling analysis next round.

static constexpr int BLOCK_S   = 512;    // scatter threads
static constexpr int EPB       = 4096;   // edges per tile
static constexpr int VITERS    = EPB / (BLOCK_S * 4);  // 2 (int4 groups)
static constexpr int CHUNK     = 256;    // nodes per bucket (pow2)
static constexpr int LOG_CHUNK = 8;
static constexpr int BLOCK_A   = 1024;   // agg threads
static constexpr int MAXNB     = 512;    // max buckets (N <= 131072)
static constexpr int MAXBLK    = 1024;   // max tiles (E <= 4.19M)
static constexpr int TABCAP    = 10240;  // run-table entries
static constexpr int PAD       = 10240;  // payload2 per-bucket capacity
static constexpr unsigned int SENT = 0xFFFFFFFFu;

// ============ 512-thread flat inclusive scan (2 barriers) ============
__device__ __forceinline__ unsigned int incl_scan512(unsigned int v,
                                                     unsigned int* wsum, int t) {
    unsigned int x = v;
#pragma unroll
    for (int off = 1; off < 64; off <<= 1) {
        unsigned int y = __shfl_up(x, off, 64);
        if ((t & 63) >= off) x += y;
    }
    if ((t & 63) == 63) wsum[t >> 6] = x;
    __syncthreads();
    if (t < 8) {
        unsigned int s = wsum[t];
#pragma unroll
        for (int off = 1; off < 8; off <<= 1) {
            unsigned int y = __shfl_up(s, off, 64);
            if (t >= off) s += y;
        }
        wsum[t] = s;
    }
    __syncthreads();
    return x + ((t >= 64) ? wsum[(t >> 6) - 1] : 0u);
}

// ============ 1024-thread flat inclusive scan (2 barriers) ============
__device__ __forceinline__ unsigned int incl_scan1024(unsigned int v,
                                                      unsigned int* wsum, int t) {
    unsigned int x = v;
#pragma unroll
    for (int off = 1; off < 64; off <<= 1) {
        unsigned int y = __shfl_up(x, off, 64);
        if ((t & 63) >= off) x += y;
    }
    if ((t & 63) == 63) wsum[t >> 6] = x;   // 16 wave sums
    __syncthreads();
    if (t < 16) {
        unsigned int s = wsum[t];
#pragma unroll
        for (int off = 1; off < 16; off <<= 1) {
            unsigned int y = __shfl_up(s, off, 64);
            if (t >= off) s += y;
        }
        wsum[t] = s;
    }
    __syncthreads();
    return x + ((t >= 64) ? wsum[(t >> 6) - 1] : 0u);
}

__device__ __forceinline__ int run_adj_fallback(const unsigned int* cumx,
                                                const int* radj,
                                                unsigned int i, int nblk) {
    int lo = 0, hi = nblk - 1;
    while (lo < hi) {
        int mid = (lo + hi + 1) >> 1;
        if (cumx[mid] <= i) lo = mid; else hi = mid - 1;
    }
    return radj[lo];
}

// ======================= K1: scatter (LDS sort, tile-major payload) =======================
__global__ __launch_bounds__(BLOCK_S) void scatter_kernel(
    const int* __restrict__ src, const int* __restrict__ dst,
    const float* __restrict__ w,
    unsigned int* __restrict__ rowOffT,        // [(nb+1)][nblk] transposed
    unsigned long long* __restrict__ payload,  // [nblk*EPB]
    int E, int nb, int nblk) {
    __shared__ unsigned long long pbuf[EPB];   // 32 KB staging
    __shared__ unsigned int hist[MAXNB];       // 2 KB (counts -> cursor)
    __shared__ unsigned int wsum[8];
    const int blk  = blockIdx.x;
    const int base = blk * EPB;
    const int nE   = min(EPB, E - base);       // multiple of 4
    const int t    = threadIdx.x;

    hist[t] = 0u;
    __syncthreads();

    int4 dc[VITERS];                           // static indexing -> VGPRs
#pragma unroll
    for (int i = 0; i < VITERS; ++i) {
        const int k = 4 * t + i * 4 * BLOCK_S;
        int4 d4 = make_int4(0, 0, 0, 0);
        if (k < nE) {
            d4 = *reinterpret_cast<const int4*>(&dst[base + k]);
            atomicAdd(&hist[(unsigned int)d4.x >> LOG_CHUNK], 1u);
            atomicAdd(&hist[(unsigned int)d4.y >> LOG_CHUNK], 1u);
            atomicAdd(&hist[(unsigned int)d4.z >> LOG_CHUNK], 1u);
            atomicAdd(&hist[(unsigned int)d4.w >> LOG_CHUNK], 1u);
        }
        dc[i] = d4;
    }
    __syncthreads();

    // flat scan: thread t owns bucket t (nb <= 512)
    const unsigned int val  = hist[t];
    const unsigned int incl = incl_scan512(val, wsum, t);
    const unsigned int excl = incl - val;
    if (t < nb)  rowOffT[(size_t)t * nblk + blk]  = excl;
    if (t == 0)  rowOffT[(size_t)nb * nblk + blk] = (unsigned int)nE;
    hist[t] = excl;                             // -> cursor
    __syncthreads();

#pragma unroll
    for (int i = 0; i < VITERS; ++i) {
        const int k = 4 * t + i * 4 * BLOCK_S;
        if (k < nE) {
            const int4   d4 = dc[i];
            const int4   s4 = *reinterpret_cast<const int4*>(&src[base + k]);
            const float4 w4 = *reinterpret_cast<const float4*>(&w[base + k]);
#define SCAT_ONE(dd, ss, ww)                                                  \
            {                                                                 \
                const unsigned int slot =                                     \
                    atomicAdd(&hist[(unsigned int)(dd) >> LOG_CHUNK], 1u);    \
                pbuf[slot] =                                                  \
                    ((unsigned long long)__float_as_uint(ww) << 32) |         \
                    ((unsigned int)(ss) << LOG_CHUNK) |                       \
                    (unsigned int)((dd) & (CHUNK - 1));                       \
            }
            SCAT_ONE(d4.x, s4.x, w4.x)
            SCAT_ONE(d4.y, s4.y, w4.y)
            SCAT_ONE(d4.z, s4.z, w4.z)
            SCAT_ONE(d4.w, s4.w, w4.w)
#undef SCAT_ONE
        }
    }
    __syncthreads();
    // coalesced, in-order global write-out, 16B per lane (nE multiple of 4)
    for (int k2 = t; k2 < (nE >> 1); k2 += BLOCK_S) {
        ulonglong2 v = *reinterpret_cast<const ulonglong2*>(&pbuf[2 * k2]);
        *reinterpret_cast<ulonglong2*>(&payload[(size_t)base + 2 * k2]) = v;
    }
}

// ======================= K2: pass A — deg + REGROUP (1024 thr) =======================
// Flat prologue (thread t owns tile t), run-offset table, 4-wide table-path
// read computes degree AND writes bucket edges contiguously to payload2.
__global__ __launch_bounds__(BLOCK_A) void deg_dinv_kernel(
    const unsigned long long* __restrict__ payload,
    unsigned long long* __restrict__ payload2,   // [nb*PAD]
    unsigned int* __restrict__ bucketCnt,        // [nb]
    const unsigned int* __restrict__ rowOffT,
    const float* __restrict__ x,
    float* __restrict__ dinv, float* __restrict__ xd,
    int N, int nb, int nblk) {
    __shared__ unsigned int cumx[MAXBLK];        // 4 KB
    __shared__ int          radj[MAXBLK];        // 4 KB
    __shared__ float        acc[CHUNK];          // 1 KB
    __shared__ int          table[TABCAP];       // 40 KB
    __shared__ unsigned int wsum[16];
    __shared__ unsigned int totsh;
    const int b = blockIdx.x, t = threadIdx.x;
    if (t < CHUNK) acc[t] = 0.0f;

    unsigned int s0 = 0, len = 0;
    if (t < nblk) {                              // coalesced rows
        s0  = rowOffT[(size_t)b * nblk + t];
        len = rowOffT[(size_t)(b + 1) * nblk + t] - s0;
    }
    const unsigned int incl = incl_scan1024(len, wsum, t);
    const unsigned int ex   = incl - len;
    if (t < nblk) { cumx[t] = ex; radj[t] = (int)s0 - (int)ex + t * EPB; }
    if (t == nblk - 1) totsh = incl;
    __syncthreads();
    const unsigned int total = totsh;
    const bool canw = (total <= (unsigned int)PAD);
    if (t == 0) bucketCnt[b] = canw ? total : SENT;
    if (t < nblk) {                              // run-offset table fill
        const unsigned int beg = cumx[t];
        const unsigned int end = (t == nblk - 1) ? total : cumx[t + 1];
        const unsigned int lim = min(end, (unsigned int)TABCAP);
        const int a_ = radj[t];
        for (unsigned int i = beg; i < lim; ++i) table[i] = a_;
    }
    __syncthreads();

#define TAB(i) (((i) < (unsigned int)TABCAP) ? table[i]                       \
                                             : run_adj_fallback(cumx, radj, (i), nblk))
    unsigned long long* const p2 = payload2 + (size_t)b * PAD;
    unsigned int i = t;
    for (; i + 3u * BLOCK_A < total; i += 4u * BLOCK_A) {
        const unsigned int i0 = i, i1 = i + BLOCK_A, i2 = i + 2u * BLOCK_A,
                           i3 = i + 3u * BLOCK_A;
        const int a0 = TAB(i0), a1 = TAB(i1), a2 = TAB(i2), a3 = TAB(i3);
        const unsigned long long p0 = payload[(unsigned int)(a0 + (int)i0)];
        const unsigned long long p1 = payload[(unsigned int)(a1 + (int)i1)];
        const unsigned long long p2v = payload[(unsigned int)(a2 + (int)i2)];
        const unsigned long long p3 = payload[(unsigned int)(a3 + (int)i3)];
        if (canw) { p2[i0] = p0; p2[i1] = p1; p2[i2] = p2v; p2[i3] = p3; }
        atomicAdd(&acc[(unsigned int)p0 & (CHUNK - 1)],
                  __uint_as_float((unsigned int)(p0 >> 32)));
        atomicAdd(&acc[(unsigned int)p1 & (CHUNK - 1)],
                  __uint_as_float((unsigned int)(p1 >> 32)));
        atomicAdd(&acc[(unsigned int)p2v & (CHUNK - 1)],
                  __uint_as_float((unsigned int)(p2v >> 32)));
        atomicAdd(&acc[(unsigned int)p3 & (CHUNK - 1)],
                  __uint_as_float((unsigned int)(p3 >> 32)));
    }
    for (; i < total; i += BLOCK_A) {
        const int adj = TAB(i);
        const unsigned long long p = payload[(unsigned int)(adj + (int)i)];
        if (canw) p2[i] = p;
        atomicAdd(&acc[(unsigned int)p & (CHUNK - 1)],
                  __uint_as_float((unsigned int)(p >> 32)));
    }
#undef TAB
    __syncthreads();
    const int n = b * CHUNK + t;
    if (t < CHUNK && n < N) {
        const float d = acc[t] + 1.0f;           // self-loop fill 1.0
        const float r = (d > 0.0f) ? rsqrtf(d) : 0.0f;
        dinv[n] = r;
        xd[n]   = r * x[n];
    }
}

// ======================= passes B/C: contiguous payload2 (1024 thr) =======================
// Fast path: ulonglong2 x4 (8 edges/thread/iter); one iteration covers a
// typical 8K-edge bucket. Fallback (cnt==SENT): flat prologue + per-edge
// binary search over payload (correctness only, never taken at +16 sigma).

#define FAST_BODY(GATHER_ARR)                                                 \
    const size_t gbase = (size_t)b * PAD;                                     \
    const unsigned int npair = cnt >> 1;                                      \
    unsigned int j = t;                                                       \
    for (; j + 3u * BLOCK_A < npair; j += 4u * BLOCK_A) {                     \
        const ulonglong2 q0 = *reinterpret_cast<const ulonglong2*>(&payload2[gbase + 2u * j]); \
        const ulonglong2 q1 = *reinterpret_cast<const ulonglong2*>(&payload2[gbase + 2u * (j + BLOCK_A)]); \
        const ulonglong2 q2 = *reinterpret_cast<const ulonglong2*>(&payload2[gbase + 2u * (j + 2u * BLOCK_A)]); \
        const ulonglong2 q3 = *reinterpret_cast<const ulonglong2*>(&payload2[gbase + 2u * (j + 3u * BLOCK_A)]); \
        const float f0a = GATHER_ARR[(int)(((unsigned int)q0.x) >> LOG_CHUNK)]; \
        const float f0b = GATHER_ARR[(int)(((unsigned int)q0.y) >> LOG_CHUNK)]; \
        const float f1a = GATHER_ARR[(int)(((unsigned int)q1.x) >> LOG_CHUNK)]; \
        const float f1b = GATHER_ARR[(int)(((unsigned int)q1.y) >> LOG_CHUNK)]; \
        const float f2a = GATHER_ARR[(int)(((unsigned int)q2.x) >> LOG_CHUNK)]; \
        const float f2b = GATHER_ARR[(int)(((unsigned int)q2.y) >> LOG_CHUNK)]; \
        const float f3a = GATHER_ARR[(int)(((unsigned int)q3.x) >> LOG_CHUNK)]; \
        const float f3b = GATHER_ARR[(int)(((unsigned int)q3.y) >> LOG_CHUNK)]; \
        atomicAdd(&acc[(unsigned int)q0.x & (CHUNK - 1)], __uint_as_float((unsigned int)(q0.x >> 32)) * f0a); \
        atomicAdd(&acc[(unsigned int)q0.y & (CHUNK - 1)], __uint_as_float((unsigned int)(q0.y >> 32)) * f0b); \
        atomicAdd(&acc[(unsigned int)q1.x & (CHUNK - 1)], __uint_as_float((unsigned int)(q1.x >> 32)) * f1a); \
        atomicAdd(&acc[(unsigned int)q1.y & (CHUNK - 1)], __uint_as_float((unsigned int)(q1.y >> 32)) * f1b); \
        atomicAdd(&acc[(unsigned int)q2.x & (CHUNK - 1)], __uint_as_float((unsigned int)(q2.x >> 32)) * f2a); \
        atomicAdd(&acc[(unsigned int)q2.y & (CHUNK - 1)], __uint_as_float((unsigned int)(q2.y >> 32)) * f2b); \
        atomicAdd(&acc[(unsigned int)q3.x & (CHUNK - 1)], __uint_as_float((unsigned int)(q3.x >> 32)) * f3a); \
        atomicAdd(&acc[(unsigned int)q3.y & (CHUNK - 1)], __uint_as_float((unsigned int)(q3.y >> 32)) * f3b); \
    }                                                                         \
    for (; j < npair; j += BLOCK_A) {                                         \
        const ulonglong2 q = *reinterpret_cast<const ulonglong2*>(&payload2[gbase + 2u * j]); \
        const float fa = GATHER_ARR[(int)(((unsigned int)q.x) >> LOG_CHUNK)]; \
        const float fb = GATHER_ARR[(int)(((unsigned int)q.y) >> LOG_CHUNK)]; \
        atomicAdd(&acc[(unsigned int)q.x & (CHUNK - 1)], __uint_as_float((unsigned int)(q.x >> 32)) * fa); \
        atomicAdd(&acc[(unsigned int)q.y & (CHUNK - 1)], __uint_as_float((unsigned int)(q.y >> 32)) * fb); \
    }                                                                         \
    if ((cnt & 1u) && t == 0) {                                               \
        const unsigned long long q = payload2[gbase + cnt - 1u];              \
        atomicAdd(&acc[(unsigned int)q & (CHUNK - 1)],                        \
                  __uint_as_float((unsigned int)(q >> 32)) *                  \
                      GATHER_ARR[(int)(((unsigned int)q) >> LOG_CHUNK)]);     \
    }

#define FB_BODY(GATHER_ARR)                                                   \
    {                                                                         \
        unsigned int s0 = 0, len = 0;                                         \
        if (t < nblk) {                                                       \
            s0  = rowOffT[(size_t)b * nblk + t];                              \
            len = rowOffT[(size_t)(b + 1) * nblk + t] - s0;                   \
        }                                                                     \
        const unsigned int incl = incl_scan1024(len, wsum, t);                \
        const unsigned int ex   = incl - len;                                 \
        if (t < nblk) { cumx[t] = ex; radj[t] = (int)s0 - (int)ex + t * EPB; } \
        if (t == nblk - 1) totsh = incl;                                      \
        __syncthreads();                                                      \
        const unsigned int total = totsh;                                     \
        for (unsigned int i = t; i < total; i += BLOCK_A) {                   \
            const int adj = run_adj_fallback(cumx, radj, i, nblk);            \
            const unsigned long long p = payload[(unsigned int)(adj + (int)i)]; \
            atomicAdd(&acc[(unsigned int)p & (CHUNK - 1)],                    \
                      __uint_as_float((unsigned int)(p >> 32)) *              \
                          GATHER_ARR[(int)(((unsigned int)p) >> LOG_CHUNK)]); \
        }                                                                     \
    }

// ---- K3: s -> relu-MLP -> gd ----
__global__ __launch_bounds__(BLOCK_A) void s_gamma_kernel(
    const unsigned long long* __restrict__ payload,
    const unsigned long long* __restrict__ payload2,
    const unsigned int* __restrict__ bucketCnt,
    const unsigned int* __restrict__ rowOffT,
    const float* __restrict__ dinv,
    const float* __restrict__ xd,
    const float* __restrict__ W1,    // [16]
    const float* __restrict__ b1,    // [16]
    const float* __restrict__ W2,    // [16][2]
    float* __restrict__ gd, int N, int nb, int nblk) {
    __shared__ unsigned int cumx[MAXBLK];
    __shared__ int          radj[MAXBLK];
    __shared__ float        acc[CHUNK];
    __shared__ unsigned int wsum[16];
    __shared__ unsigned int totsh;
    const int b = blockIdx.x, t = threadIdx.x;
    const unsigned int cnt = bucketCnt[b];
    if (t < CHUNK) acc[t] = 0.0f;
    __syncthreads();
    if (cnt != SENT) {          // uniform per-block branch
        FAST_BODY(xd)
    } else {
        FB_BODY(xd)
    }
    __syncthreads();
    const int n = b * CHUNK + t;
    if (t < CHUNK && n < N) {
        const float dv = dinv[n];
        const float sv = dv * (acc[t] + xd[n]);   // + self-loop dv*dv*x[n]
        float g = 0.0f;
#pragma unroll
        for (int f = 0; f < 16; ++f) {
            const float h = fmaxf(sv * W1[f] + b1[f], 0.0f);   // relu(layer1)
            g += h * (W2[2 * f + 1] - W2[2 * f + 0]);          // gamma = g1-g0
        }
        gd[n] = dv * g;                           // pre-scaled for layer 2
    }
}

// ---- K4: d -> log_softmax out ----
__global__ __launch_bounds__(BLOCK_A) void d_out_kernel(
    const unsigned long long* __restrict__ payload,
    const unsigned long long* __restrict__ payload2,
    const unsigned int* __restrict__ bucketCnt,
    const unsigned int* __restrict__ rowOffT,
    const float* __restrict__ dinv,
    const float* __restrict__ gd,
    const float* __restrict__ b2,    // [2]
    float* __restrict__ out, int N, int nb, int nblk) {
    __shared__ unsigned int cumx[MAXBLK];
    __shared__ int          radj[MAXBLK];
    __shared__ float        acc[CHUNK];
    __shared__ unsigned int wsum[16];
    __shared__ unsigned int totsh;
    const int b = blockIdx.x, t = threadIdx.x;
    const unsigned int cnt = bucketCnt[b];
    if (t < CHUNK) acc[t] = 0.0f;
    __syncthreads();
    if (cnt != SENT) {
        FAST_BODY(gd)
    } else {
        FB_BODY(gd)
    }
    __syncthreads();
    const int n = b * CHUNK + t;
    if (t < CHUNK && n < N) {
        const float dv = dinv[n];
        const float d = dv * (acc[t] + gd[n]) + (b2[1] - b2[0]);
        // 2-class log_softmax from d = a1 - a0 (stable)
        const float lse = fmaxf(d, 0.0f) + log1pf(expf(-fabsf(d)));
        out[2 * n + 0] = -lse;
        out[2 * n + 1] = d - lse;
    }
}

// ======================= fallback: R3 global-atomic path =======================

static constexpr int BLOCK = 256;

__global__ void zero_kernel(float* __restrict__ a, float* __restrict__ b, int n2) {
    int i = blockIdx.x * blockDim.x + threadIdx.x;
    if (i < n2) { a[i] = 0.0f; b[i] = 0.0f; }
}
__global__ void deg_kernel(const int* __restrict__ dst, const float* __restrict__ w,
                           float* __restrict__ deg, int E) {
    int e = blockIdx.x * blockDim.x + threadIdx.x;
    if (e < E) atomicAdd(&deg[dst[e]], w[e]);
}
__global__ void dinv_kernel(float* __restrict__ deg, int N) {
    int n = blockIdx.x * blockDim.x + threadIdx.x;
    if (n < N) {
        float d = deg[n] + 1.0f;
        deg[n] = (d > 0.0f) ? rsqrtf(d) : 0.0f;
    }
}
__global__ void s_kernel(const int* __restrict__ src, const int* __restrict__ dst,
                         const float* __restrict__ w, const float* __restrict__ dinv,
                         const float* __restrict__ x, float* __restrict__ s, int E) {
    int e = blockIdx.x * blockDim.x + threadIdx.x;
    if (e < E) {
        int si = src[e], di = dst[e];
        atomicAdd(&s[di], dinv[si] * w[e] * dinv[di] * x[si]);
    }
}
__global__ void g_kernel(const float* __restrict__ s, const float* __restrict__ dinv,
                         const float* __restrict__ x, const float* __restrict__ W1,
                         const float* __restrict__ b1, const float* __restrict__ W2,
                         float2* __restrict__ g, int N) {
    int n = blockIdx.x * blockDim.x + threadIdx.x;
    if (n < N) {
        float dv = dinv[n];
        float sv = s[n] + dv * dv * x[n];
        float g0 = 0.0f, g1 = 0.0f;
#pragma unroll
        for (int f = 0; f < 16; ++f) {
            float h = fmaxf(sv * W1[f] + b1[f], 0.0f);
            g0 += h * W2[2 * f + 0];
            g1 += h * W2[2 * f + 1];
        }
        g[n] = make_float2(g0, g1);
    }
}
__global__ void agg2_kernel(const int* __restrict__ src, const int* __restrict__ dst,
                            const float* __restrict__ w, const float* __restrict__ dinv,
                            const float2* __restrict__ g, float* __restrict__ agg, int E) {
    int e = blockIdx.x * blockDim.x + threadIdx.x;
    if (e < E) {
        int si = src[e], di = dst[e];
        float norm = dinv[si] * w[e] * dinv[di];
        float2 gv = g[si];
        atomicAdd(&agg[2 * di + 0], norm * gv.x);
        atomicAdd(&agg[2 * di + 1], norm * gv.y);
    }
}
__global__ void out_kernel(float* __restrict__ out, const float* __restrict__ dinv,
                           const float2* __restrict__ g, const float* __restrict__ b2, int N) {
    int n = blockIdx.x * blockDim.x + threadIdx.x;
    if (n < N) {
        float dv2 = dinv[n] * dinv[n];
        float2 gv = g[n];
        float a0 = out[2 * n + 0] + dv2 * gv.x + b2[0];
        float a1 = out[2 * n + 1] + dv2 * gv.y + b2[1];
        float m = fmaxf(a0, a1);
        float lse = m + logf(expf(a0 - m) + expf(a1 - m));
        out[2 * n + 0] = a0 - lse;
        out[2 * n + 1] = a1 - lse;
    }
}

// ======================= launch =======================

extern "C" void kernel_launch(void* const* d_in, const int* in_sizes, int n_in,
                              void* d_out, int out_size, void* d_ws, size_t ws_size,
                              hipStream_t stream) {
    const float* x  = (const float*)d_in[0];
    const int*   ei = (const int*)d_in[1];     // [2, E] delivered as int32
    const float* w  = (const float*)d_in[2];
    const float* W1 = (const float*)d_in[3];
    const float* b1 = (const float*)d_in[4];
    const float* W2 = (const float*)d_in[5];
    const float* b2 = (const float*)d_in[6];
    float* out = (float*)d_out;

    const int N = in_sizes[0];
    const int E = in_sizes[2];
    const int* src = ei;
    const int* dst = ei + E;

    const int nb   = (N + CHUNK - 1) / CHUNK;   // 391
    const int nblk = (E + EPB - 1) / EPB;       // 782

    // ws layout: payload | payload2 | rowOffT | bucketCnt | dinv | xd | gd
    size_t off = 0;
    auto align16 = [](size_t v) { return (v + 15) & ~(size_t)15; };
    size_t payload_off  = off;  off = align16(off + (size_t)nblk * EPB * 8);
    size_t payload2_off = off;  off = align16(off + (size_t)nb * PAD * 8);
    size_t rowoff_off   = off;  off = align16(off + (size_t)(nb + 1) * nblk * 4);
    size_t bcnt_off     = off;  off = align16(off + (size_t)nb * 4);
    size_t dinv_off     = off;  off = align16(off + (size_t)N * 4);
    size_t xd_off       = off;  off = align16(off + (size_t)N * 4);
    size_t gd_off       = off;  off = align16(off + (size_t)N * 4);
    const size_t required = off;

    const bool fits = (nb <= MAXNB && nb <= BLOCK_S && nblk <= MAXBLK &&
                       nblk <= BLOCK_A && (E % 4) == 0 && ws_size >= required);

    if (fits) {
        char* wsb = (char*)d_ws;
        unsigned long long* payload  = (unsigned long long*)(wsb + payload_off);
        unsigned long long* payload2 = (unsigned long long*)(wsb + payload2_off);
        unsigned int* rowOffT   = (unsigned int*)(wsb + rowoff_off);
        unsigned int* bucketCnt = (unsigned int*)(wsb + bcnt_off);
        float* dinv = (float*)(wsb + dinv_off);
        float* xd   = (float*)(wsb + xd_off);
        float* gd   = (float*)(wsb + gd_off);

        scatter_kernel <<<nblk, BLOCK_S, 0, stream>>>(src, dst, w, rowOffT, payload,
                                                      E, nb, nblk);
        deg_dinv_kernel<<<nb, BLOCK_A, 0, stream>>>(payload, payload2, bucketCnt,
                                                    rowOffT, x, dinv, xd, N, nb, nblk);
        s_gamma_kernel <<<nb, BLOCK_A, 0, stream>>>(payload, payload2, bucketCnt,
                                                    rowOffT, dinv, xd,
                                                    W1, b1, W2, gd, N, nb, nblk);
        d_out_kernel   <<<nb, BLOCK_A, 0, stream>>>(payload, payload2, bucketCnt,
                                                    rowOffT, dinv, gd, b2,
                                                    out, N, nb, nblk);
    } else {
        // R3 fallback: global-atomic path (needs 4N floats of ws)
        float*  ws   = (float*)d_ws;
        float*  dinv = ws;
        float*  s    = ws + (size_t)N;
        float2* g    = (float2*)(ws + (size_t)2 * N);
        const int gridE  = (E + BLOCK - 1) / BLOCK;
        const int gridN  = (N + BLOCK - 1) / BLOCK;
        const int gridN2 = (2 * N + BLOCK - 1) / BLOCK;
        zero_kernel<<<gridN2, BLOCK, 0, stream>>>(ws, out, 2 * N);
        deg_kernel <<<gridE,  BLOCK, 0, stream>>>(dst, w, dinv, E);
        dinv_kernel<<<gridN,  BLOCK, 0, stream>>>(dinv, N);
        s_kernel   <<<gridE,  BLOCK, 0, stream>>>(src, dst, w, dinv, x, s, E);
        g_kernel   <<<gridN,  BLOCK, 0, stream>>>(s, dinv, x, W1, b1, W2, g, N);
        agg2_kernel<<<gridE,  BLOCK, 0, stream>>>(src, dst, w, dinv, g, out, E);
        out_kernel <<<gridN,  BLOCK, 0, stream>>>(out, dinv, g, b2, N);
    }
}